// Round 2
// baseline (3046.913 us; speedup 1.0000x reference)
//
#include <hip/hip_runtime.h>

#define BB 64
#define SS 2048
#define HH 128

// ---------------------------------------------------------------------------
// GEMM: out[row][j] = in[row][:] @ W[:][j] + bias[j], K=N=128. (proven, ~120us)
// ---------------------------------------------------------------------------
__global__ __launch_bounds__(256) void gemm128v2(const float* __restrict__ in,
                                                 const float* __restrict__ W,
                                                 const float* __restrict__ bias,
                                                 float* __restrict__ out) {
  __shared__ __align__(16) float xls[128 * 128];   // 64 KB
  __shared__ __align__(16) float wls[128 * 140];   // 70 KB (padded rows)
  const int t = threadIdx.x;
  const long row0 = (long)blockIdx.x * 128;

  {
    const float4* g4 = (const float4*)(in + row0 * 128);
    float4* l4 = (float4*)xls;
#pragma unroll
    for (int it = 0; it < 16; ++it) l4[t + 256 * it] = g4[t + 256 * it];
  }
  {
#pragma unroll
    for (int it = 0; it < 16; ++it) {
      const int fidx = (t + 256 * it) * 4;
      const int k = fidx >> 7, j = fidx & 127;
      const float4 v = *(const float4*)(W + fidx);
      *(float4*)(wls + k * 140 + j + 4 * (j >> 5)) = v;
    }
  }
  __syncthreads();

  const int rg = t >> 4, cg = t & 15;
  const float* xrow = xls + (rg * 8) * 128;
  const float* wcol = wls + cg * 8 + 4 * (cg >> 2);

  float4 acc0[8], acc1[8];
#pragma unroll
  for (int r = 0; r < 8; ++r) {
    acc0[r] = make_float4(0.f, 0.f, 0.f, 0.f);
    acc1[r] = make_float4(0.f, 0.f, 0.f, 0.f);
  }

  for (int k = 0; k < 128; k += 4) {
    float4 xv[8];
#pragma unroll
    for (int r = 0; r < 8; ++r) xv[r] = *(const float4*)(xrow + r * 128 + k);
#pragma unroll
    for (int kk = 0; kk < 4; ++kk) {
      const float* wr = wcol + (k + kk) * 140;
      const float4 w0 = *(const float4*)(wr);
      const float4 w1 = *(const float4*)(wr + 4);
#pragma unroll
      for (int r = 0; r < 8; ++r) {
        const float xs = (kk == 0) ? xv[r].x : (kk == 1) ? xv[r].y
                       : (kk == 2) ? xv[r].z : xv[r].w;
        acc0[r].x = fmaf(xs, w0.x, acc0[r].x);
        acc0[r].y = fmaf(xs, w0.y, acc0[r].y);
        acc0[r].z = fmaf(xs, w0.z, acc0[r].z);
        acc0[r].w = fmaf(xs, w0.w, acc0[r].w);
        acc1[r].x = fmaf(xs, w1.x, acc1[r].x);
        acc1[r].y = fmaf(xs, w1.y, acc1[r].y);
        acc1[r].z = fmaf(xs, w1.z, acc1[r].z);
        acc1[r].w = fmaf(xs, w1.w, acc1[r].w);
      }
    }
  }

  const float4 b0 = *(const float4*)(bias + cg * 8);
  const float4 b1 = *(const float4*)(bias + cg * 8 + 4);
  float* op = out + (row0 + rg * 8) * 128 + cg * 8;
#pragma unroll
  for (int r = 0; r < 8; ++r) {
    float4 o0, o1;
    o0.x = acc0[r].x + b0.x; o0.y = acc0[r].y + b0.y;
    o0.z = acc0[r].z + b0.z; o0.w = acc0[r].w + b0.w;
    o1.x = acc1[r].x + b1.x; o1.y = acc1[r].y + b1.y;
    o1.z = acc1[r].z + b1.z; o1.w = acc1[r].w + b1.w;
    *(float4*)(op + r * 128) = o0;
    *(float4*)(op + r * 128 + 4) = o1;
  }
}

// ---------------------------------------------------------------------------
// Recurrence: h_t = relu(tanh(xi_t + h_{t-1} @ Wh)).
// ONE WAVE per batch row (64 WGs x 64 threads). Lane j owns output cols
// {2j, 2j+1} with the FULL k=128 weight slice in registers (w2[128] float2 =
// 256 VGPRs; __launch_bounds__(64,1) -> 512-VGPR budget, 1 wave/SIMD).
// Consequences (R1 post-mortem: every per-step instruction is paid 2048x):
//   - NO cross-lane reduction (no shuffles; R1's xor4/xor8 levels were
//     ds_swizzle ops with LDS latency on the critical path)
//   - NO s_barrier (single wave; ds_write -> lgkmcnt -> ds_read orders the
//     h broadcast; compiler inserts the waits via may-alias on hbuf)
//   - tanh fully lane-parallel (2 cols/lane)
// h broadcast: 32 uniform-address ds_read_b128 (conflict-free broadcast) +
// one ds_write_b64/lane (stride 8B = 2-way bank alias, free per m136).
// Floor: 256 FMA/lane/step x 2cyc = 512 cyc wave64 issue; step ~750-810.
// ---------------------------------------------------------------------------
__global__ __launch_bounds__(64, 1) void rnn_rec1w(float* __restrict__ xi,
                                                   const float* __restrict__ Wh) {
  __shared__ __align__(16) float hbuf[2][128];
  const int j = threadIdx.x;   // 0..63, owns cols 2j, 2j+1
  const int j2 = 2 * j;

  // weights: w2[k] = Wh[k][j2..j2+1] -> 256 VGPRs (coalesced 8B-lane loads)
  float2 w2[128];
#pragma unroll
  for (int k = 0; k < 128; ++k) w2[k] = *(const float2*)(Wh + k * HH + j2);

  // h_{-1} = 0
  hbuf[0][j] = 0.0f;
  hbuf[0][j + 64] = 0.0f;

  float* xb = xi + (size_t)blockIdx.x * SS * HH + j2;

  // xi prefetch, PF steps deep (~6000 cyc of cover); consumed at step t,
  // slot overwritten with the hs store at step t (same address, long after).
  constexpr int PF = 8;
  float2 pre[PF];
#pragma unroll
  for (int p = 0; p < PF; ++p) pre[p] = *(const float2*)(xb + (size_t)p * HH);

  for (int t0 = 0; t0 < SS; t0 += PF) {
#pragma unroll
    for (int p = 0; p < PF; ++p) {
      const int t = t0 + p;
      const float4* h4 = (const float4*)hbuf[p & 1];  // t&1==p&1 (PF even)

      // 8 independent chains (4 per col): 32 FMAs deep, issue-interleaved
      float ax[4] = {0.f, 0.f, 0.f, 0.f};
      float bx[4] = {0.f, 0.f, 0.f, 0.f};
#pragma unroll
      for (int q = 0; q < 32; ++q) {
        const float4 hv = h4[q];  // uniform addr: LDS broadcast, no conflict
        const float2 wA = w2[4 * q + 0], wB = w2[4 * q + 1];
        const float2 wC = w2[4 * q + 2], wD = w2[4 * q + 3];
        const int c = q & 3;  // static (unrolled) -- stays in registers
        ax[c] = fmaf(hv.x, wA.x, ax[c]);
        ax[c] = fmaf(hv.y, wB.x, ax[c]);
        ax[c] = fmaf(hv.z, wC.x, ax[c]);
        ax[c] = fmaf(hv.w, wD.x, ax[c]);
        bx[c] = fmaf(hv.x, wA.y, bx[c]);
        bx[c] = fmaf(hv.y, wB.y, bx[c]);
        bx[c] = fmaf(hv.z, wC.y, bx[c]);
        bx[c] = fmaf(hv.w, wD.y, bx[c]);
      }
      const float sa = ((ax[0] + ax[1]) + (ax[2] + ax[3])) + pre[p].x;
      const float sb = ((bx[0] + bx[1]) + (bx[2] + bx[3])) + pre[p].y;

      // tanh(v) = 1 - 2/(exp2(2v*log2e)+1); safe at +-inf. relu via fmax.
      const float ea = __builtin_amdgcn_exp2f(sa * 2.8853900817779268f);
      const float eb = __builtin_amdgcn_exp2f(sb * 2.8853900817779268f);
      float2 hn;
      hn.x = fmaxf(1.0f - 2.0f * __builtin_amdgcn_rcpf(ea + 1.0f), 0.0f);
      hn.y = fmaxf(1.0f - 2.0f * __builtin_amdgcn_rcpf(eb + 1.0f), 0.0f);

      *(float2*)(&hbuf[(p & 1) ^ 1][j2]) = hn;  // h for step t+1 (dbuf)
      *(float2*)(xb + (size_t)t * HH) = hn;     // hs for the output GEMM

      const int tn = t + PF;
      if (tn < SS) pre[p] = *(const float2*)(xb + (size_t)tn * HH);
    }
  }
}

extern "C" void kernel_launch(void* const* d_in, const int* in_sizes, int n_in,
                              void* d_out, int out_size, void* d_ws, size_t ws_size,
                              hipStream_t stream) {
  const float* x  = (const float*)d_in[0];
  const float* Wi = (const float*)d_in[1];
  const float* Wh = (const float*)d_in[2];
  const float* b  = (const float*)d_in[3];
  const float* Wo = (const float*)d_in[4];
  const float* bo = (const float*)d_in[5];
  float* y  = (float*)d_out;
  float* xi = (float*)d_ws;  // 64 MB: xi = x@Wi+b, overwritten in-place with hs

  gemm128v2<<<(BB * SS) / 128, 256, 0, stream>>>(x, Wi, b, xi);
  rnn_rec1w<<<BB, 64, 0, stream>>>(xi, Wh);
  gemm128v2<<<(BB * SS) / 128, 256, 0, stream>>>(xi, Wo, bo, y);
}

// Round 3
// 991.803 us; speedup vs baseline: 3.0721x; 3.0721x over previous
//
#include <hip/hip_runtime.h>

#define BB 64
#define SS 2048
#define HH 128

// LDS-only barrier: drains DS ops (lgkmcnt) but NOT outstanding global
// loads/stores -- keeps per-step prefetch/stores off the critical path.
__device__ __forceinline__ void lds_barrier() {
  asm volatile("s_waitcnt lgkmcnt(0)\n\ts_barrier" ::: "memory");
}

// ---------------------------------------------------------------------------
// GEMM: out[row][j] = in[row][:] @ W[:][j] + bias[j], K=N=128. (proven)
// ---------------------------------------------------------------------------
__global__ __launch_bounds__(256) void gemm128v2(const float* __restrict__ in,
                                                 const float* __restrict__ W,
                                                 const float* __restrict__ bias,
                                                 float* __restrict__ out) {
  __shared__ __align__(16) float xls[128 * 128];   // 64 KB
  __shared__ __align__(16) float wls[128 * 140];   // 70 KB (padded rows)
  const int t = threadIdx.x;
  const long row0 = (long)blockIdx.x * 128;

  {
    const float4* g4 = (const float4*)(in + row0 * 128);
    float4* l4 = (float4*)xls;
#pragma unroll
    for (int it = 0; it < 16; ++it) l4[t + 256 * it] = g4[t + 256 * it];
  }
  {
#pragma unroll
    for (int it = 0; it < 16; ++it) {
      const int fidx = (t + 256 * it) * 4;
      const int k = fidx >> 7, j = fidx & 127;
      const float4 v = *(const float4*)(W + fidx);
      *(float4*)(wls + k * 140 + j + 4 * (j >> 5)) = v;
    }
  }
  __syncthreads();

  const int rg = t >> 4, cg = t & 15;
  const float* xrow = xls + (rg * 8) * 128;
  const float* wcol = wls + cg * 8 + 4 * (cg >> 2);

  float4 acc0[8], acc1[8];
#pragma unroll
  for (int r = 0; r < 8; ++r) {
    acc0[r] = make_float4(0.f, 0.f, 0.f, 0.f);
    acc1[r] = make_float4(0.f, 0.f, 0.f, 0.f);
  }

  for (int k = 0; k < 128; k += 4) {
    float4 xv[8];
#pragma unroll
    for (int r = 0; r < 8; ++r) xv[r] = *(const float4*)(xrow + r * 128 + k);
#pragma unroll
    for (int kk = 0; kk < 4; ++kk) {
      const float* wr = wcol + (k + kk) * 140;
      const float4 w0 = *(const float4*)(wr);
      const float4 w1 = *(const float4*)(wr + 4);
#pragma unroll
      for (int r = 0; r < 8; ++r) {
        const float xs = (kk == 0) ? xv[r].x : (kk == 1) ? xv[r].y
                       : (kk == 2) ? xv[r].z : xv[r].w;
        acc0[r].x = fmaf(xs, w0.x, acc0[r].x);
        acc0[r].y = fmaf(xs, w0.y, acc0[r].y);
        acc0[r].z = fmaf(xs, w0.z, acc0[r].z);
        acc0[r].w = fmaf(xs, w0.w, acc0[r].w);
        acc1[r].x = fmaf(xs, w1.x, acc1[r].x);
        acc1[r].y = fmaf(xs, w1.y, acc1[r].y);
        acc1[r].z = fmaf(xs, w1.z, acc1[r].z);
        acc1[r].w = fmaf(xs, w1.w, acc1[r].w);
      }
    }
  }

  const float4 b0 = *(const float4*)(bias + cg * 8);
  const float4 b1 = *(const float4*)(bias + cg * 8 + 4);
  float* op = out + (row0 + rg * 8) * 128 + cg * 8;
#pragma unroll
  for (int r = 0; r < 8; ++r) {
    float4 o0, o1;
    o0.x = acc0[r].x + b0.x; o0.y = acc0[r].y + b0.y;
    o0.z = acc0[r].z + b0.z; o0.w = acc0[r].w + b0.w;
    o1.x = acc1[r].x + b1.x; o1.y = acc1[r].y + b1.y;
    o1.z = acc1[r].z + b1.z; o1.w = acc1[r].w + b1.w;
    *(float4*)(op + r * 128) = o0;
    *(float4*)(op + r * 128 + 4) = o1;
  }
}

// ---------------------------------------------------------------------------
// Recurrence: h_t = relu(tanh(xi_t + h_{t-1} @ Wh)).
// R2 post-mortem: weight ARRAYS fail SROA -> scratch reload every step
// (R2: VGPR=152 w/ 256-float array; R0: VGPR=56 w/ 64-float array -> R0's
// 1009cyc/step was scratch-reload-bound, not LDS-bound). Fixes here:
//   (a) weights are 16 NAMED float4 (W0..W15) -- nothing for SROA to bail on
//   (b) __launch_bounds__(256, 1) so the allocator targets 1 wave/SIMD,
//       not the ~56-VGPR 8-wave budget the bare (256) hint produced.
// Decomposition: jg=tid>>3 (32 col-groups x 4 cols), kg=tid&7 (8 k-slices
// of 16). Per lane: 64 FMA (128cyc issue), 4x ds_read_b128 (16 wave-instr
// /step/CU, half of R0). h stored as 8 chunks of 16 floats at stride 20:
// the 8 distinct broadcast addresses per read cover all 32 banks.
// Reduce over kg: weight COMPONENTS are permuted per-lane at load time
// (comp i = col c0^i, c0=kg&3) so every fold level is a static
// p.x + shfl_xor(p.y, d): xor1/xor2 = DPP quad_perm, xor4 = one ds_swizzle.
// Zero cndmasks in the loop. Lane ends with full sum for col jg*4+(kg&3);
// kg<4 lanes apply xi+tanh+relu and write h (LDS dbuf) + hs (global).
// ---------------------------------------------------------------------------
#define F4(s, W, A)                                                   \
  A.x = fmaf(s, W.x, A.x); A.y = fmaf(s, W.y, A.y);                   \
  A.z = fmaf(s, W.z, A.z); A.w = fmaf(s, W.w, A.w);

__global__ __launch_bounds__(256, 1) void rnn_rec4w(float* __restrict__ xi,
                                                    const float* __restrict__ Wh) {
  __shared__ __align__(16) float hbuf[2][160];  // 8 chunks x (16+4 pad)
  const int tid = threadIdx.x;
  const int jg = tid >> 3;  // col-group: cols jg*4 .. jg*4+3
  const int kg = tid & 7;   // k-slice:  k    kg*16 .. kg*16+15

  // per-lane component permutation for the static reduce tree
  const int c0 = kg & 3, c1 = c0 ^ 1, c2 = c0 ^ 2, c3 = c0 ^ 3;
  const float* wbase = Wh + (kg * 16) * HH + jg * 4;
#define LDW(q) make_float4(wbase[(q) * HH + c0], wbase[(q) * HH + c1], \
                           wbase[(q) * HH + c2], wbase[(q) * HH + c3])
  const float4 W0 = LDW(0),  W1 = LDW(1),  W2 = LDW(2),  W3 = LDW(3);
  const float4 W4 = LDW(4),  W5 = LDW(5),  W6 = LDW(6),  W7 = LDW(7);
  const float4 W8 = LDW(8),  W9 = LDW(9),  W10 = LDW(10), W11 = LDW(11);
  const float4 W12 = LDW(12), W13 = LDW(13), W14 = LDW(14), W15 = LDW(15);
#undef LDW

  if (tid < 160) hbuf[0][tid] = 0.0f;  // h_{-1} = 0 (incl. pads)

  const int col = jg * 4 + c0;                     // owned col (kg<4 lanes)
  const int hwoff = (col >> 4) * 20 + (col & 15);  // chunked write slot
  float* xb = xi + (size_t)blockIdx.x * SS * HH + col;

  // xi prefetch: 1 float/lane (owned col), PF steps deep
  constexpr int PF = 8;
  float pre[PF];
  if (kg < 4) {
#pragma unroll
    for (int p = 0; p < PF; ++p) pre[p] = xb[(size_t)p * HH];
  }
  __syncthreads();

  const float* hrd0 = hbuf[0] + kg * 20;
  const float* hrd1 = hbuf[1] + kg * 20;

  for (int t0 = 0; t0 < SS; t0 += PF) {
#pragma unroll
    for (int p = 0; p < PF; ++p) {
      const int t = t0 + p;
      const float4* h4 = (const float4*)((p & 1) ? hrd1 : hrd0);
      const float4 hv0 = h4[0], hv1 = h4[1], hv2 = h4[2], hv3 = h4[3];

      float4 a0 = make_float4(0.f, 0.f, 0.f, 0.f);
      float4 a1 = make_float4(0.f, 0.f, 0.f, 0.f);
      float4 a2 = make_float4(0.f, 0.f, 0.f, 0.f);
      float4 a3 = make_float4(0.f, 0.f, 0.f, 0.f);
      F4(hv0.x, W0, a0)  F4(hv0.y, W1, a1)  F4(hv0.z, W2, a2)  F4(hv0.w, W3, a3)
      F4(hv1.x, W4, a0)  F4(hv1.y, W5, a1)  F4(hv1.z, W6, a2)  F4(hv1.w, W7, a3)
      F4(hv2.x, W8, a0)  F4(hv2.y, W9, a1)  F4(hv2.z, W10, a2) F4(hv2.w, W11, a3)
      F4(hv3.x, W12, a0) F4(hv3.y, W13, a1) F4(hv3.z, W14, a2) F4(hv3.w, W15, a3)

      float4 pp;
      pp.x = (a0.x + a1.x) + (a2.x + a3.x);  // col c0 partial
      pp.y = (a0.y + a1.y) + (a2.y + a3.y);  // col c0^1
      pp.z = (a0.z + a1.z) + (a2.z + a3.z);  // col c0^2
      pp.w = (a0.w + a1.w) + (a2.w + a3.w);  // col c0^3
      // static reduce-scatter over kg (partner's permutation supplies
      // exactly my col): xor1/xor2 are DPP quad_perm, xor4 one ds_swizzle.
      const float q0 = pp.x + __shfl_xor(pp.y, 1);
      const float q1 = pp.z + __shfl_xor(pp.w, 1);
      const float rr = q0 + __shfl_xor(q1, 2);
      const float ss = rr + __shfl_xor(rr, 4);

      if (kg < 4) {
        const float v = ss + pre[p];
        // tanh(v) = 1 - 2/(exp2(2v*log2e)+1); safe at +-inf. relu via fmax.
        const float e = __builtin_amdgcn_exp2f(v * 2.8853900817779268f);
        const float hn =
            fmaxf(1.0f - 2.0f * __builtin_amdgcn_rcpf(e + 1.0f), 0.0f);
        hbuf[(p & 1) ^ 1][hwoff] = hn;   // h for step t+1 (dbuf)
        xb[(size_t)t * HH] = hn;         // hs for the output GEMM
        const int tn = t + PF;
        if (tn < SS) pre[p] = xb[(size_t)tn * HH];
      }
      lds_barrier();
    }
  }
}

extern "C" void kernel_launch(void* const* d_in, const int* in_sizes, int n_in,
                              void* d_out, int out_size, void* d_ws, size_t ws_size,
                              hipStream_t stream) {
  const float* x  = (const float*)d_in[0];
  const float* Wi = (const float*)d_in[1];
  const float* Wh = (const float*)d_in[2];
  const float* b  = (const float*)d_in[3];
  const float* Wo = (const float*)d_in[4];
  const float* bo = (const float*)d_in[5];
  float* y  = (float*)d_out;
  float* xi = (float*)d_ws;  // 64 MB: xi = x@Wi+b, overwritten in-place with hs

  gemm128v2<<<(BB * SS) / 128, 256, 0, stream>>>(x, Wi, b, xi);
  rnn_rec4w<<<BB, 256, 0, stream>>>(xi, Wh);
  gemm128v2<<<(BB * SS) / 128, 256, 0, stream>>>(xi, Wo, bo, y);
}